// Round 1
// baseline (163.626 us; speedup 1.0000x reference)
//
#include <hip/hip_runtime.h>
#include <stdint.h>

typedef __bf16 bf16_t;
typedef __bf16 bf16x8 __attribute__((ext_vector_type(8)));
typedef float floatx4 __attribute__((ext_vector_type(4)));

#define B_ 8
#define N_ 2048
#define D_ 768
#define H_ 64

__device__ __forceinline__ bf16_t f2bf(float f) {
    union { float f; uint32_t u; } v; v.f = f;
    uint32_t u = v.u;
    uint32_t r = (u + 0x7fffu + ((u >> 16) & 1u)) >> 16;
    union { unsigned short s; bf16_t b; } o; o.s = (unsigned short)r;
    return o.b;
}

// ---------------------------------------------------------------------------
// Kernel 1: W transpose + cast.  Wt[n][k], n in [0,192): 0-63 Wq, 64-127 Wk,
// 128-191 Wv columns.  Row-major 192x768 bf16 so B-fragments are contiguous.
// ---------------------------------------------------------------------------
__global__ void wt_kernel(const float* __restrict__ Wq,
                          const float* __restrict__ Wk,
                          const float* __restrict__ Wv,
                          bf16_t* __restrict__ Wt) {
    int idx = blockIdx.x * 256 + threadIdx.x;   // 0 .. 192*768-1
    if (idx >= 192 * D_) return;
    int n = idx / D_;
    int k = idx - n * D_;
    const float* W = (n < 64) ? Wq : (n < 128) ? Wk : Wv;
    int h = n & 63;
    Wt[idx] = f2bf(W[k * H_ + h]);
}

// ---------------------------------------------------------------------------
// Kernel 2: fused QKV projection.  M=16384 rows, K=768, N=192.
// Block = 4 waves, each wave owns 16 rows, all 192 output cols (12 n-tiles).
// Outputs: Qb,Kb as (b,n,64) bf16 row-major; V stored transposed Vt (b,64,n).
// ---------------------------------------------------------------------------
__launch_bounds__(256)
__global__ void proj_kernel(const float* __restrict__ X,
                            const bf16_t* __restrict__ Wt,
                            bf16_t* __restrict__ Qb,
                            bf16_t* __restrict__ Kb,
                            bf16_t* __restrict__ Vt) {
    const int wave = threadIdx.x >> 6;
    const int lane = threadIdx.x & 63;
    const int quad = lane >> 4;
    const int l16  = lane & 15;
    const int m0 = blockIdx.x * 64 + wave * 16;   // wave's first row

    floatx4 acc[12];
#pragma unroll
    for (int i = 0; i < 12; i++) acc[i] = (floatx4){0.f, 0.f, 0.f, 0.f};

    const float* xrow = X + (size_t)(m0 + l16) * D_;

    for (int k0 = 0; k0 < D_; k0 += 32) {
        const int kbase = k0 + quad * 8;
        float4 xa = *(const float4*)(xrow + kbase);
        float4 xb = *(const float4*)(xrow + kbase + 4);
        bf16x8 afrag;
        afrag[0] = f2bf(xa.x); afrag[1] = f2bf(xa.y);
        afrag[2] = f2bf(xa.z); afrag[3] = f2bf(xa.w);
        afrag[4] = f2bf(xb.x); afrag[5] = f2bf(xb.y);
        afrag[6] = f2bf(xb.z); afrag[7] = f2bf(xb.w);
#pragma unroll
        for (int nt = 0; nt < 12; nt++) {
            bf16x8 bfrag = *(const bf16x8*)(Wt + (size_t)(nt * 16 + l16) * D_ + kbase);
            acc[nt] = __builtin_amdgcn_mfma_f32_16x16x32_bf16(afrag, bfrag, acc[nt], 0, 0, 0);
        }
    }

    // D layout: row = quad*4 + r (within wave's 16 rows), col = nt*16 + l16
#pragma unroll
    for (int nt = 0; nt < 12; nt++) {
        const int c = nt * 16 + l16;          // 0..191
#pragma unroll
        for (int r = 0; r < 4; r++) {
            const int m = m0 + quad * 4 + r;  // global row (b*2048 + n)
            bf16_t val = f2bf(acc[nt][r]);
            if (c < 64) {
                Qb[(size_t)m * H_ + c] = val;
            } else if (c < 128) {
                Kb[(size_t)m * H_ + (c - 64)] = val;
            } else {
                const int b = m >> 11, n = m & 2047, h = c - 128;
                Vt[((size_t)b * H_ + h) * N_ + n] = val;
            }
        }
    }
}

// ---------------------------------------------------------------------------
// Kernel 3: flash attention, causal.  q-tile 32 rows, k-tile 32 keys.
// 4 waves: wave&1 -> q-row half (16 rows), wave>>1 -> k-tile parity.
// Partials (O, m, l) merged across parities through LDS at the end.
// K,V fragments loaded straight from global (Kb row-major, Vt transposed).
// ---------------------------------------------------------------------------
__launch_bounds__(256)
__global__ void attn_kernel(const bf16_t* __restrict__ Qb,
                            const bf16_t* __restrict__ Kb,
                            const bf16_t* __restrict__ Vt,
                            float* __restrict__ Out) {
    const int x = blockIdx.x;            // 0..31
    const int b = blockIdx.y;            // 0..7
    const int z = blockIdx.z;            // 0..1
    const int qt = z ? (63 - x) : x;     // causal load-balance pairing
    const int q0 = qt * 32;

    const int wave = threadIdx.x >> 6;
    const int lane = threadIdx.x & 63;
    const int quad = lane >> 4;
    const int l16  = lane & 15;
    const int rowhalf = wave & 1;
    const int kpar    = wave >> 1;

    const int qbase = q0 + rowhalf * 16;
    const bf16_t* Qp = Qb + ((size_t)b * N_ + qbase) * H_;
    const bf16_t* Kp = Kb + (size_t)b * N_ * H_;
    const bf16_t* Vp = Vt + (size_t)b * H_ * N_;

    // Q fragments for the wave's 16 rows, 2 h-chunks of 32
    bf16x8 qf0 = *(const bf16x8*)(Qp + (size_t)l16 * H_ + quad * 8);
    bf16x8 qf1 = *(const bf16x8*)(Qp + (size_t)l16 * H_ + 32 + quad * 8);

    floatx4 o[4];
#pragma unroll
    for (int i = 0; i < 4; i++) o[i] = (floatx4){0.f, 0.f, 0.f, 0.f};
    float mrow[4], lrow[4];
#pragma unroll
    for (int r = 0; r < 4; r++) { mrow[r] = -3e38f; lrow[r] = 0.f; }

    const float c = 0.125f * 1.4426950408889634f;   // log2(e) / sqrt(H)

    __shared__ __align__(16) bf16_t Pl[4][16][32];
    __shared__ float Ol[2][16][64];
    __shared__ float Ml[2][16], Ll[2][16];

    const int kt_max = (qbase + 15) >> 5;   // inclusive

    for (int kt = kpar; kt <= kt_max; kt += 2) {
        const int k0 = kt << 5;
        // ---- S = Q K^T (16 q x 32 keys), fp32 accum ----
        floatx4 s0 = (floatx4){0.f, 0.f, 0.f, 0.f};
        floatx4 s1 = (floatx4){0.f, 0.f, 0.f, 0.f};
        const bf16_t* kp0 = Kp + (size_t)(k0 + l16) * H_ + quad * 8;
        const bf16_t* kp1 = Kp + (size_t)(k0 + 16 + l16) * H_ + quad * 8;
        bf16x8 kfa = *(const bf16x8*)(kp0);
        bf16x8 kfb = *(const bf16x8*)(kp0 + 32);
        bf16x8 kfc = *(const bf16x8*)(kp1);
        bf16x8 kfd = *(const bf16x8*)(kp1 + 32);
        s0 = __builtin_amdgcn_mfma_f32_16x16x32_bf16(qf0, kfa, s0, 0, 0, 0);
        s0 = __builtin_amdgcn_mfma_f32_16x16x32_bf16(qf1, kfb, s0, 0, 0, 0);
        s1 = __builtin_amdgcn_mfma_f32_16x16x32_bf16(qf0, kfc, s1, 0, 0, 0);
        s1 = __builtin_amdgcn_mfma_f32_16x16x32_bf16(qf1, kfd, s1, 0, 0, 0);

        // ---- causal mask + online softmax ----
        const int qrow = qbase + quad * 4;
        float sm[8];
#pragma unroll
        for (int r = 0; r < 4; r++) {
            sm[r]     = (k0 + l16      <= qrow + r) ? s0[r] : -3e38f;
            sm[4 + r] = (k0 + 16 + l16 <= qrow + r) ? s1[r] : -3e38f;
        }
        float rmax[4];
#pragma unroll
        for (int r = 0; r < 4; r++) rmax[r] = fmaxf(sm[r], sm[4 + r]);
#pragma unroll
        for (int off = 1; off < 16; off <<= 1) {
#pragma unroll
            for (int r = 0; r < 4; r++)
                rmax[r] = fmaxf(rmax[r], __shfl_xor(rmax[r], off, 64));
        }
        float alpha[4];
#pragma unroll
        for (int r = 0; r < 4; r++) {
            float mnew = fmaxf(mrow[r], rmax[r]);
            alpha[r] = exp2f((mrow[r] - mnew) * c);
            mrow[r] = mnew;
            lrow[r] *= alpha[r];
        }
        float p[8];
#pragma unroll
        for (int i = 0; i < 8; i++) {
            int r = i & 3;
            p[i] = exp2f((sm[i] - mrow[r]) * c);   // masked -> 0
        }
        float rsum[4];
#pragma unroll
        for (int r = 0; r < 4; r++) rsum[r] = p[r] + p[4 + r];
#pragma unroll
        for (int off = 1; off < 16; off <<= 1) {
#pragma unroll
            for (int r = 0; r < 4; r++) rsum[r] += __shfl_xor(rsum[r], off, 64);
        }
#pragma unroll
        for (int r = 0; r < 4; r++) lrow[r] += rsum[r];
#pragma unroll
        for (int nt = 0; nt < 4; nt++)
#pragma unroll
            for (int r = 0; r < 4; r++) o[nt][r] *= alpha[r];

        // ---- P: C-layout -> A-layout via wave-private LDS (in-order DS) ----
#pragma unroll
        for (int r = 0; r < 4; r++) {
            Pl[wave][quad * 4 + r][l16]      = f2bf(p[r]);
            Pl[wave][quad * 4 + r][16 + l16] = f2bf(p[4 + r]);
        }
        bf16x8 pf = *(const bf16x8*)(&Pl[wave][l16][quad * 8]);

        // ---- O += P V  (B-frags straight from transposed V) ----
        const bf16_t* vp = Vp + (size_t)l16 * N_ + k0 + quad * 8;
#pragma unroll
        for (int nt = 0; nt < 4; nt++) {
            bf16x8 vf = *(const bf16x8*)(vp + (size_t)(nt * 16) * N_);
            o[nt] = __builtin_amdgcn_mfma_f32_16x16x32_bf16(pf, vf, o[nt], 0, 0, 0);
        }
    }

    // ---- merge k-parity partials ----
    __syncthreads();
    if (kpar == 1) {
#pragma unroll
        for (int nt = 0; nt < 4; nt++)
#pragma unroll
            for (int r = 0; r < 4; r++)
                Ol[rowhalf][quad * 4 + r][nt * 16 + l16] = o[nt][r];
        if (l16 == 0) {
#pragma unroll
            for (int r = 0; r < 4; r++) {
                Ml[rowhalf][quad * 4 + r] = mrow[r];
                Ll[rowhalf][quad * 4 + r] = lrow[r];
            }
        }
    }
    __syncthreads();
    if (kpar == 0) {
#pragma unroll
        for (int r = 0; r < 4; r++) {
            const int row = quad * 4 + r;
            float m2 = Ml[rowhalf][row], l2 = Ll[rowhalf][row];
            float mt = fmaxf(mrow[r], m2);
            float a1 = exp2f((mrow[r] - mt) * c);
            float a2 = exp2f((m2 - mt) * c);
            float inv = 1.0f / (lrow[r] * a1 + l2 * a2);
#pragma unroll
            for (int nt = 0; nt < 4; nt++) {
                float val = (o[nt][r] * a1 + Ol[rowhalf][row][nt * 16 + l16] * a2) * inv;
                Out[((size_t)b * N_ + qbase + row) * H_ + nt * 16 + l16] = val;
            }
        }
    }
}

// ---------------------------------------------------------------------------
extern "C" void kernel_launch(void* const* d_in, const int* in_sizes, int n_in,
                              void* d_out, int out_size, void* d_ws, size_t ws_size,
                              hipStream_t stream) {
    const float* X  = (const float*)d_in[0];
    const float* Wq = (const float*)d_in[1];
    const float* Wk = (const float*)d_in[2];
    const float* Wv = (const float*)d_in[3];
    float* Out = (float*)d_out;

    char* ws = (char*)d_ws;
    bf16_t* Qb = (bf16_t*)(ws);                         // 2 MiB
    bf16_t* Kb = (bf16_t*)(ws + (size_t)(2u << 20));    // 2 MiB
    bf16_t* Vt = (bf16_t*)(ws + (size_t)(4u << 20));    // 2 MiB (transposed)
    bf16_t* Wt = (bf16_t*)(ws + (size_t)(6u << 20));    // 288 KiB

    hipLaunchKernelGGL(wt_kernel, dim3(576), dim3(256), 0, stream, Wq, Wk, Wv, Wt);
    hipLaunchKernelGGL(proj_kernel, dim3(256), dim3(256), 0, stream, X, Wt, Qb, Kb, Vt);
    hipLaunchKernelGGL(attn_kernel, dim3(32, 8, 2), dim3(256), 0, stream, Qb, Kb, Vt, Out);
}